// Round 3
// baseline (86.994 us; speedup 1.0000x reference)
//
#include <hip/hip_runtime.h>

// ExemplarHead fused single-kernel:
// logits[t,q,w,s] = -||Qc - proj_s||^2 / d, proj = Rc M, M = (G+lam I)^-1 G  (Gram trick, no SVD)
// dist[q,s] = ||Qc_q||^2 - 2*(C^T Qc_q)·M[:,s] + (M^T G M)[s,s]
// Grid (T, NW, 5): each block redundantly preps its (t,w) (cheap, L2/L3-resident)
// then its 4 waves each handle 4 queries jointly (C LDS reads amortized 4x).

constexpr int   T_   = 32;
constexpr int   NW   = 5;
constexpr int   NS   = 5;
constexpr int   NQ   = 75;
constexpr int   D    = 1024;
constexpr int   D4   = D / 4;
constexpr float LAM  = 100000.0f;

__global__ __launch_bounds__(256) void exemplar_fused_kernel(
    const float* __restrict__ query,    // (T, NQ, D)
    const float* __restrict__ support,  // (T, NW*NS, D)
    const float* __restrict__ noise,    // (NW, T, NS, D)
    float* __restrict__ out)            // (T, NQ, NW, NS)
{
    const int t    = blockIdx.x;
    const int w    = blockIdx.y;
    const int tid  = threadIdx.x;
    const int lane = tid & 63;
    const int wave = tid >> 6;

    __shared__ float CsF[NS * D];    // centered class reps
    __shared__ float meanS[D];
    __shared__ float gpart[4][15];
    __shared__ float MsS[25];        // M = (G+lam I)^-1 G
    __shared__ float pdS[NS];        // diag(M^T G M)

    // ---- Phase 1: load support+noise, mean, center, stash C in LDS ----
    const float4* sup4 = (const float4*)(support + (size_t)(t * NW * NS + w * NS) * D);
    const float4* noi4 = (const float4*)(noise   + (size_t)((w * T_ + t) * NS) * D);
    float4 r[NS];
    float4 sum = make_float4(0.f, 0.f, 0.f, 0.f);
#pragma unroll
    for (int s = 0; s < NS; ++s) {
        float4 a = sup4[s * D4 + tid];
        float4 b = noi4[s * D4 + tid];
        float4 v = make_float4(a.x + b.x, a.y + b.y, a.z + b.z, a.w + b.w);
        r[s] = v;
        sum.x += v.x; sum.y += v.y; sum.z += v.z; sum.w += v.w;
    }
    float4 mn = make_float4(sum.x * 0.2f, sum.y * 0.2f, sum.z * 0.2f, sum.w * 0.2f);
    ((float4*)meanS)[tid] = mn;
#pragma unroll
    for (int s = 0; s < NS; ++s) {
        r[s].x -= mn.x; r[s].y -= mn.y; r[s].z -= mn.z; r[s].w -= mn.w;
        ((float4*)CsF)[s * D4 + tid] = r[s];
    }

    // ---- Gram partials (15 unique entries) ----
    {
        float g[15];
        int n = 0;
#pragma unroll
        for (int k = 0; k < NS; ++k)
#pragma unroll
            for (int l = k; l < NS; ++l)
                g[n++] = r[k].x * r[l].x + r[k].y * r[l].y +
                         r[k].z * r[l].z + r[k].w * r[l].w;
#pragma unroll
        for (int off = 1; off < 64; off <<= 1)
#pragma unroll
            for (int m = 0; m < 15; ++m)
                g[m] += __shfl_xor(g[m], off, 64);
        if (lane == 0)
#pragma unroll
            for (int m = 0; m < 15; ++m) gpart[wave][m] = g[m];
    }
    __syncthreads();

    // ---- Phase 2: 5x5 Gauss-Jordan on thread 0 (lam-dominated, no pivoting) ----
    if (tid == 0) {
        float G[NS][NS];
        int n = 0;
        for (int k = 0; k < NS; ++k)
            for (int l = k; l < NS; ++l) {
                float v = gpart[0][n] + gpart[1][n] + gpart[2][n] + gpart[3][n];
                ++n;
                G[k][l] = v; G[l][k] = v;
            }
        float A[NS][2 * NS];
        for (int i = 0; i < NS; ++i)
            for (int j = 0; j < NS; ++j) {
                A[i][j]      = G[i][j] + (i == j ? LAM : 0.0f);
                A[i][NS + j] = G[i][j];
            }
        for (int c = 0; c < NS; ++c) {
            float inv = 1.0f / A[c][c];
            for (int j = 0; j < 2 * NS; ++j) A[c][j] *= inv;
            for (int rI = 0; rI < NS; ++rI) {
                if (rI == c) continue;
                float f = A[rI][c];
                for (int j = 0; j < 2 * NS; ++j) A[rI][j] -= f * A[c][j];
            }
        }
        float M[NS][NS];
        for (int i = 0; i < NS; ++i)
            for (int j = 0; j < NS; ++j) {
                M[i][j] = A[i][NS + j];
                MsS[i * NS + j] = M[i][j];
            }
        for (int s = 0; s < NS; ++s) {
            float acc = 0.f;
            for (int i = 0; i < NS; ++i) {
                float gi = 0.f;
                for (int j = 0; j < NS; ++j) gi += G[i][j] * M[j][s];
                acc += M[i][s] * gi;
            }
            pdS[s] = acc;
        }
    }
    __syncthreads();

    // ---- Phase 3: 4 queries per wave, jointly per j (C reads amortized 4x) ----
    const int qbase = blockIdx.z * 16 + wave * 4;
    const float4* q4base = (const float4*)(query + (size_t)t * NQ * D);

    const float4* qp[4];
    bool valid[4];
#pragma unroll
    for (int qi = 0; qi < 4; ++qi) {
        int q = qbase + qi;
        valid[qi] = (q < NQ);
        qp[qi] = q4base + (size_t)(valid[qi] ? q : 0) * D4;
    }

    float acc[4][NS];
    float sq[4];
#pragma unroll
    for (int qi = 0; qi < 4; ++qi) {
        sq[qi] = 0.f;
#pragma unroll
        for (int k = 0; k < NS; ++k) acc[qi][k] = 0.f;
    }

#pragma unroll
    for (int j = 0; j < 4; ++j) {
        const int i4 = lane + 64 * j;
        float4 m = ((const float4*)meanS)[i4];
        float4 qc[4];
#pragma unroll
        for (int qi = 0; qi < 4; ++qi) {
            float4 qq = qp[qi][i4];
            qc[qi] = make_float4(qq.x - m.x, qq.y - m.y, qq.z - m.z, qq.w - m.w);
            sq[qi] += qc[qi].x * qc[qi].x + qc[qi].y * qc[qi].y +
                      qc[qi].z * qc[qi].z + qc[qi].w * qc[qi].w;
        }
#pragma unroll
        for (int k = 0; k < NS; ++k) {
            float4 c = ((const float4*)CsF)[k * D4 + i4];
#pragma unroll
            for (int qi = 0; qi < 4; ++qi)
                acc[qi][k] += qc[qi].x * c.x + qc[qi].y * c.y +
                              qc[qi].z * c.z + qc[qi].w * c.w;
        }
    }

    // butterfly reduce 24 values across the wave
#pragma unroll
    for (int off = 1; off < 64; off <<= 1) {
#pragma unroll
        for (int qi = 0; qi < 4; ++qi) {
            sq[qi] += __shfl_xor(sq[qi], off, 64);
#pragma unroll
            for (int k = 0; k < NS; ++k)
                acc[qi][k] += __shfl_xor(acc[qi][k], off, 64);
        }
    }

    if (lane < NS) {
        const int s = lane;
#pragma unroll
        for (int qi = 0; qi < 4; ++qi) {
            if (!valid[qi]) continue;
            const int q = qbase + qi;
            float dot = 0.f;
#pragma unroll
            for (int k = 0; k < NS; ++k) dot += acc[qi][k] * MsS[k * NS + s];
            float dist = sq[qi] - 2.0f * dot + pdS[s];
            out[(((size_t)t * NQ + q) * NW + w) * NS + s] = -dist * (1.0f / (float)D);
        }
    }
}

extern "C" void kernel_launch(void* const* d_in, const int* in_sizes, int n_in,
                              void* d_out, int out_size, void* d_ws, size_t ws_size,
                              hipStream_t stream) {
    const float* query   = (const float*)d_in[0];
    const float* support = (const float*)d_in[1];
    const float* noise   = (const float*)d_in[2];
    float* out = (float*)d_out;

    dim3 grid(T_, NW, (NQ + 15) / 16);   // (32, 5, 5) = 800 blocks
    exemplar_fused_kernel<<<grid, 256, 0, stream>>>(query, support, noise, out);
}

// Round 4
// 85.883 us; speedup vs baseline: 1.0129x; 1.0129x over previous
//
#include <hip/hip_runtime.h>

// ExemplarHead fused single-kernel (R4):
// logits[t,q,w,s] = -||Qc - proj_s||^2 / d, proj = Rc M, M = (G+lam I)^-1 G  (Gram trick, no SVD)
// dist[q,s] = ||Qc_q||^2 - 2*(C^T Qc_q)·M[:,s] + (M^T G M)[s,s]
// Grid (T, NW, 5): each block preps its (t,w) (L2/L3-resident redundancy),
// 5x5 solve is WAVE-PARALLEL on wave 0 (row-per-lane GJ, readlane broadcasts),
// then 4 waves x 4 queries jointly (C LDS reads amortized 4x).

constexpr int   T_   = 32;
constexpr int   NW   = 5;
constexpr int   NS   = 5;
constexpr int   NQ   = 75;
constexpr int   D    = 1024;
constexpr int   D4   = D / 4;
constexpr float LAM  = 100000.0f;

// (k,l) index tables for the 15 unique Gram entries, packed as nibbles (n=0 lowest)
constexpr unsigned long long KPACK = 0x433222111100000ULL;
constexpr unsigned long long LPACK = 0x443432432143210ULL;

__global__ __launch_bounds__(256) void exemplar_fused_kernel(
    const float* __restrict__ query,    // (T, NQ, D)
    const float* __restrict__ support,  // (T, NW*NS, D)
    const float* __restrict__ noise,    // (NW, T, NS, D)
    float* __restrict__ out)            // (T, NQ, NW, NS)
{
    const int t    = blockIdx.x;
    const int w    = blockIdx.y;
    const int tid  = threadIdx.x;
    const int lane = tid & 63;
    const int wave = tid >> 6;

    __shared__ float CsF[NS * D];    // centered class reps
    __shared__ float meanS[D];
    __shared__ float gpart[4][15];   // per-wave Gram partials
    __shared__ float GsS[25];        // full symmetric G
    __shared__ float MsS[25];        // M = (G+lam I)^-1 G
    __shared__ float pdS[NS];        // diag(M^T G M)

    // ---- Phase 1: load support+noise, mean, center, stash C in LDS ----
    const float4* sup4 = (const float4*)(support + (size_t)(t * NW * NS + w * NS) * D);
    const float4* noi4 = (const float4*)(noise   + (size_t)((w * T_ + t) * NS) * D);
    float4 r[NS];
    float4 sum = make_float4(0.f, 0.f, 0.f, 0.f);
#pragma unroll
    for (int s = 0; s < NS; ++s) {
        float4 a = sup4[s * D4 + tid];
        float4 b = noi4[s * D4 + tid];
        float4 v = make_float4(a.x + b.x, a.y + b.y, a.z + b.z, a.w + b.w);
        r[s] = v;
        sum.x += v.x; sum.y += v.y; sum.z += v.z; sum.w += v.w;
    }
    float4 mn = make_float4(sum.x * 0.2f, sum.y * 0.2f, sum.z * 0.2f, sum.w * 0.2f);
    ((float4*)meanS)[tid] = mn;
#pragma unroll
    for (int s = 0; s < NS; ++s) {
        r[s].x -= mn.x; r[s].y -= mn.y; r[s].z -= mn.z; r[s].w -= mn.w;
        ((float4*)CsF)[s * D4 + tid] = r[s];
    }

    // ---- Gram partials (15 unique entries) ----
    {
        float g[15];
        int n = 0;
#pragma unroll
        for (int k = 0; k < NS; ++k)
#pragma unroll
            for (int l = k; l < NS; ++l)
                g[n++] = r[k].x * r[l].x + r[k].y * r[l].y +
                         r[k].z * r[l].z + r[k].w * r[l].w;
#pragma unroll
        for (int off = 1; off < 64; off <<= 1)
#pragma unroll
            for (int m = 0; m < 15; ++m)
                g[m] += __shfl_xor(g[m], off, 64);
        if (lane == 0)
#pragma unroll
            for (int m = 0; m < 15; ++m) gpart[wave][m] = g[m];
    }
    __syncthreads();

    // ---- Phase 2: wave-0 parallel 5x5 solve (same-wave LDS ops are in-order) ----
    if (wave == 0) {
        // 2a: assemble full G (lanes 0..14, two symmetric slots each)
        if (lane < 15) {
            float gs = gpart[0][lane] + gpart[1][lane] + gpart[2][lane] + gpart[3][lane];
            int k = (int)((KPACK >> (4 * lane)) & 15ULL);
            int l = (int)((LPACK >> (4 * lane)) & 15ULL);
            GsS[k * NS + l] = gs;
            GsS[l * NS + k] = gs;
        }
        // 2b: row-per-lane Gauss-Jordan on [G+lam*I | G] -> [I | M]
        {
            const int i = lane % NS;   // lanes >=5 duplicate rows; only lanes 0..4 are read
            float a[10];
#pragma unroll
            for (int j = 0; j < NS; ++j) {
                float gij = GsS[i * NS + j];
                a[j]      = gij + (j == i ? LAM : 0.0f);
                a[NS + j] = gij;
            }
#pragma unroll
            for (int c = 0; c < NS; ++c) {
                float pr[10];
#pragma unroll
                for (int j = 0; j < 10; ++j) pr[j] = __shfl(a[j], c, 64);
                float inv = 1.0f / pr[c];
                if (i == c) {
#pragma unroll
                    for (int j = 0; j < 10; ++j) a[j] = pr[j] * inv;
                } else {
                    float f = a[c] * inv;
#pragma unroll
                    for (int j = 0; j < 10; ++j) a[j] -= f * pr[j];
                }
            }
            if (lane < NS)
#pragma unroll
                for (int j = 0; j < NS; ++j) MsS[lane * NS + j] = a[NS + j];
        }
        // 2c: pd[s] = M[:,s]^T G M[:,s]  (lanes 0..4)
        if (lane < NS) {
            const int s = lane;
            float m_col[NS];
#pragma unroll
            for (int i = 0; i < NS; ++i) m_col[i] = MsS[i * NS + s];
            float acc = 0.f;
#pragma unroll
            for (int i = 0; i < NS; ++i) {
                float gi = 0.f;
#pragma unroll
                for (int j = 0; j < NS; ++j) gi += GsS[i * NS + j] * m_col[j];
                acc += m_col[i] * gi;
            }
            pdS[s] = acc;
        }
    }
    __syncthreads();

    // ---- Phase 3: 4 queries per wave, jointly per j (C reads amortized 4x) ----
    const int qbase = blockIdx.z * 16 + wave * 4;
    const float4* q4base = (const float4*)(query + (size_t)t * NQ * D);

    const float4* qp[4];
    bool valid[4];
#pragma unroll
    for (int qi = 0; qi < 4; ++qi) {
        int q = qbase + qi;
        valid[qi] = (q < NQ);
        qp[qi] = q4base + (size_t)(valid[qi] ? q : 0) * D4;
    }

    float acc[4][NS];
    float sq[4];
#pragma unroll
    for (int qi = 0; qi < 4; ++qi) {
        sq[qi] = 0.f;
#pragma unroll
        for (int k = 0; k < NS; ++k) acc[qi][k] = 0.f;
    }

#pragma unroll
    for (int j = 0; j < 4; ++j) {
        const int i4 = lane + 64 * j;
        float4 m = ((const float4*)meanS)[i4];
        float4 qc[4];
#pragma unroll
        for (int qi = 0; qi < 4; ++qi) {
            float4 qq = qp[qi][i4];
            qc[qi] = make_float4(qq.x - m.x, qq.y - m.y, qq.z - m.z, qq.w - m.w);
            sq[qi] += qc[qi].x * qc[qi].x + qc[qi].y * qc[qi].y +
                      qc[qi].z * qc[qi].z + qc[qi].w * qc[qi].w;
        }
#pragma unroll
        for (int k = 0; k < NS; ++k) {
            float4 c = ((const float4*)CsF)[k * D4 + i4];
#pragma unroll
            for (int qi = 0; qi < 4; ++qi)
                acc[qi][k] += qc[qi].x * c.x + qc[qi].y * c.y +
                              qc[qi].z * c.z + qc[qi].w * c.w;
        }
    }

    // butterfly reduce 24 values across the wave
#pragma unroll
    for (int off = 1; off < 64; off <<= 1) {
#pragma unroll
        for (int qi = 0; qi < 4; ++qi) {
            sq[qi] += __shfl_xor(sq[qi], off, 64);
#pragma unroll
            for (int k = 0; k < NS; ++k)
                acc[qi][k] += __shfl_xor(acc[qi][k], off, 64);
        }
    }

    if (lane < NS) {
        const int s = lane;
#pragma unroll
        for (int qi = 0; qi < 4; ++qi) {
            if (!valid[qi]) continue;
            const int q = qbase + qi;
            float dot = 0.f;
#pragma unroll
            for (int k = 0; k < NS; ++k) dot += acc[qi][k] * MsS[k * NS + s];
            float dist = sq[qi] - 2.0f * dot + pdS[s];
            out[(((size_t)t * NQ + q) * NW + w) * NS + s] = -dist * (1.0f / (float)D);
        }
    }
}

extern "C" void kernel_launch(void* const* d_in, const int* in_sizes, int n_in,
                              void* d_out, int out_size, void* d_ws, size_t ws_size,
                              hipStream_t stream) {
    const float* query   = (const float*)d_in[0];
    const float* support = (const float*)d_in[1];
    const float* noise   = (const float*)d_in[2];
    float* out = (float*)d_out;

    dim3 grid(T_, NW, (NQ + 15) / 16);   // (32, 5, 5) = 800 blocks
    exemplar_fused_kernel<<<grid, 256, 0, stream>>>(query, support, noise, out);
}